// Round 5
// baseline (315.432 us; speedup 1.0000x reference)
//
#include <hip/hip_runtime.h>
#include <hip/hip_bf16.h>

#define NIMG 256
#define CIN  256
#define PIX  784
#define DD   64
#define NP   200
#define NPP  208   // prototypes padded to 13*16
#define NCLS 10
#define NSTRIP 49  // 784 / 16 exactly -> no pixel padding anywhere

#define XS 264     // row stride (bf16) xbuf/w1lds (256 + 8; 528 B rows, 16B-aligned)
#define HS 72      // row stride (bf16) hbuf/protolds (64 + 8; 144 B rows, 16B-aligned)

typedef __attribute__((ext_vector_type(8))) short bf16x8;
typedef __attribute__((ext_vector_type(4))) float f32x4;
typedef __attribute__((ext_vector_type(4))) unsigned int u32x4;

__device__ __forceinline__ unsigned short f2bf(float f) {
    union { float f; unsigned int u; } v; v.f = f;
    unsigned int r = v.u + 0x7fffu + ((v.u >> 16) & 1u);   // RNE
    return (unsigned short)(r >> 16);
}
__device__ __forceinline__ unsigned int pk2(float a, float b) {
    __hip_bfloat162 p = __float22bfloat162_rn(make_float2(a, b));
    return *(unsigned int*)&p;
}

#define MFMA(a, b, c) __builtin_amdgcn_mfma_f32_16x16x32_bf16((a), (b), (c), 0, 0, 0)
// In-wave LDS write->read fence: waits this wave's DS ops to commit. DS pipe is
// in-order per wave; this + compiler may-alias ordering makes the same-wave
// cross-lane round trip safe WITHOUT s_barrier (all hazards here are intra-wave).
#define LGK() __asm__ volatile("s_waitcnt lgkmcnt(0)" ::: "memory")

__global__ __launch_bounds__(512, 2)
void proto_fused_kernel(const float* __restrict__ x,
                        const float* __restrict__ W1, const float* __restrict__ b1,
                        const float* __restrict__ W2, const float* __restrict__ b2,
                        const float* __restrict__ proto,
                        const float* __restrict__ lastW, const float* __restrict__ lastb,
                        float* __restrict__ out)
{
    __shared__ __align__(16) unsigned short xbuf[8][16 * XS];   // 67.6 KB, per-wave [px][c]
    __shared__ __align__(16) unsigned short w1lds[64 * XS];     // 33.8 KB, [o][c]
    __shared__ __align__(16) unsigned short hbuf[8][16 * HS];   // 18.4 KB, per-wave h then f
    __shared__ __align__(16) unsigned short protolds[NPP * HS]; // 30.0 KB, [p][d]
    __shared__ float p2lds[NPP];
    __shared__ float b1lds[DD], b2lds[DD];
    __shared__ unsigned int bmin[NPP];

    const int n    = blockIdx.x;
    const int t    = threadIdx.x;
    const int lane = t & 63;
    const int wave = t >> 6;
    const int q    = lane >> 4;
    const int l15  = lane & 15;

    // per-wave contiguous strip range: counts {6,6,6,6,6,6,6,7}
    const int sBeg = (wave * NSTRIP) >> 3;
    const int sEnd = ((wave + 1) * NSTRIP) >> 3;

    // ---- strip load/store lane map: lane covers 4 px x 16 c ----
    // px4 from bits 2-3, c-group from bits 0-1 | 4-5: store banks spread all 8
    // quads (2-way pairs only); loads: lanes (cg fixed, px4 0/4/8/12) form 64 B
    // contiguous segments per c-row.
    const int px4 = ((lane >> 2) & 3) * 4;
    const int cg  = (lane & 3) | ((lane >> 4) << 2);   // 0..15
    const int c16 = cg * 16;
    const float* xn = x + (size_t)n * CIN * PIX;

    float4 pf[16];
    auto load_strip = [&](int s) {
        const float* base = xn + s * 16 + px4;
        #pragma unroll
        for (int j = 0; j < 16; ++j)
            pf[j] = *(const float4*)(base + (size_t)(c16 + j) * PIX);
    };
    auto store_strip = [&]() {   // register transpose -> 8x ds_write_b128 (own strip buf)
        #pragma unroll
        for (int r = 0; r < 4; ++r) {
            u32x4 u0, u1;
            u0.x = pk2(((const float*)&pf[ 0])[r], ((const float*)&pf[ 1])[r]);
            u0.y = pk2(((const float*)&pf[ 2])[r], ((const float*)&pf[ 3])[r]);
            u0.z = pk2(((const float*)&pf[ 4])[r], ((const float*)&pf[ 5])[r]);
            u0.w = pk2(((const float*)&pf[ 6])[r], ((const float*)&pf[ 7])[r]);
            u1.x = pk2(((const float*)&pf[ 8])[r], ((const float*)&pf[ 9])[r]);
            u1.y = pk2(((const float*)&pf[10])[r], ((const float*)&pf[11])[r]);
            u1.z = pk2(((const float*)&pf[12])[r], ((const float*)&pf[13])[r]);
            u1.w = pk2(((const float*)&pf[14])[r], ((const float*)&pf[15])[r]);
            *(u32x4*)&xbuf[wave][(px4 + r) * XS + c16]     = u0;
            *(u32x4*)&xbuf[wave][(px4 + r) * XS + c16 + 8] = u1;
        }
    };

    // ---- issue first strip's loads immediately (overlap with staging) ----
    load_strip(sBeg);

    // ---- W2 B-fragments direct from global into registers ----
    bf16x8 w2f[4][2];
    #pragma unroll
    for (int dt = 0; dt < 4; ++dt) {
        #pragma unroll
        for (int kk = 0; kk < 2; ++kk) {
            const float4* src = (const float4*)(W2 + (size_t)(dt * 16 + l15) * DD + kk * 32 + q * 8);
            float4 a = src[0], b = src[1];
            union { u32x4 u; bf16x8 h; } cv;
            cv.u.x = pk2(a.x, a.y); cv.u.y = pk2(a.z, a.w);
            cv.u.z = pk2(b.x, b.y); cv.u.w = pk2(b.z, b.w);
            w2f[dt][kk] = cv.h;
        }
    }

    // ---- cooperative staging: W1, protos, p2, biases, bmin ----
    for (int i = 0; i < 32; ++i) {               // W1: 64x256
        int idx = t + i * 512;
        w1lds[(idx >> 8) * XS + (idx & 255)] = f2bf(W1[idx]);
    }
    for (int i = 0; i < 25; ++i) {               // protos: 200x64 (25*512 exact)
        int idx = t + i * 512;
        protolds[(idx >> 6) * HS + (idx & 63)] = f2bf(proto[idx]);
    }
    {   // zero pad proto rows 200..207
        int p = NP + (t >> 6), d = t & 63;
        protolds[p * HS + d] = 0;
    }
    if (t < DD) { b1lds[t] = b1[t]; b2lds[t] = b2[t]; }
    if (t < NPP) {
        float acc = 0.f;
        if (t < NP) {
            const float4* pp = (const float4*)(proto + t * DD);
            #pragma unroll
            for (int i = 0; i < 16; ++i) {
                float4 v = pp[i];
                acc += v.x * v.x + v.y * v.y + v.z * v.z + v.w * v.w;
            }
        }
        p2lds[t] = acc;
        bmin[t] = 0x7f800000u;   // +inf bits (dist >= 0)
    }
    __syncthreads();   // the ONLY barrier before the final reduction

    // ---- hoist per-lane constants ----
    float b1r[4], b2r[4];
    #pragma unroll
    for (int dt = 0; dt < 4; ++dt) {
        b1r[dt] = b1lds[dt * 16 + l15];
        b2r[dt] = b2lds[dt * 16 + l15];
    }
    float p2r[13];
    #pragma unroll
    for (int pt = 0; pt < 13; ++pt) p2r[pt] = p2lds[pt * 16 + l15];

    float rmin[13];
    #pragma unroll
    for (int pt = 0; pt < 13; ++pt) rmin[pt] = 1e30f;

    unsigned short* xw = &xbuf[wave][0];
    unsigned short* hw = &hbuf[wave][0];

    // ================= barrier-free per-wave strip loop =================
    for (int s = sBeg; s < sEnd; ++s) {
        store_strip();                       // pf -> own xbuf
        if (s + 1 < sEnd) load_strip(s + 1); // in flight across full strip compute
        LGK();                               // xbuf writes visible to all own lanes

        // ---- GEMM1: 16px x 64d x 256c ----
        f32x4 acc[4] = {{0,0,0,0},{0,0,0,0},{0,0,0,0},{0,0,0,0}};
        #pragma unroll
        for (int kk = 0; kk < 8; ++kk) {
            bf16x8 a = *(const bf16x8*)&xw[l15 * XS + kk * 32 + q * 8];
            #pragma unroll
            for (int dt = 0; dt < 4; ++dt) {
                bf16x8 b = *(const bf16x8*)&w1lds[(dt * 16 + l15) * XS + kk * 32 + q * 8];
                acc[dt] = MFMA(a, b, acc[dt]);
            }
        }
        #pragma unroll
        for (int dt = 0; dt < 4; ++dt)
            #pragma unroll
            for (int r = 0; r < 4; ++r)
                hw[(q * 4 + r) * HS + dt * 16 + l15] =
                    f2bf(fmaxf(acc[dt][r] + b1r[dt], 0.f));
        LGK();                               // h visible

        // ---- GEMM2: 16px x 64d x 64d ----
        bf16x8 ha0 = *(const bf16x8*)&hw[l15 * HS + q * 8];
        bf16x8 ha1 = *(const bf16x8*)&hw[l15 * HS + 32 + q * 8];
        f32x4 acc2[4] = {{0,0,0,0},{0,0,0,0},{0,0,0,0},{0,0,0,0}};
        #pragma unroll
        for (int dt = 0; dt < 4; ++dt) {
            acc2[dt] = MFMA(ha0, w2f[dt][0], acc2[dt]);
            acc2[dt] = MFMA(ha1, w2f[dt][1], acc2[dt]);
        }
        float fv[4][4];
        #pragma unroll
        for (int dt = 0; dt < 4; ++dt)
            #pragma unroll
            for (int r = 0; r < 4; ++r) {
                float z = acc2[dt][r] + b2r[dt];
                fv[dt][r] = __builtin_amdgcn_rcpf(1.0f + __builtin_amdgcn_exp2f(z * -1.44269504f));
            }

        // ---- s2 per pixel row, fully in-wave (rows q*4+r match GEMM3 C rows) ----
        float s2v[4];
        #pragma unroll
        for (int r = 0; r < 4; ++r) {
            float v = 0.f;
            #pragma unroll
            for (int dt = 0; dt < 4; ++dt) v += fv[dt][r] * fv[dt][r];
            v += __shfl_xor(v, 1, 64);
            v += __shfl_xor(v, 2, 64);
            v += __shfl_xor(v, 4, 64);
            v += __shfl_xor(v, 8, 64);
            s2v[r] = v;
        }

        // ---- f overwrites h in place (reads above precede via data dep + order) ----
        #pragma unroll
        for (int dt = 0; dt < 4; ++dt)
            #pragma unroll
            for (int r = 0; r < 4; ++r)
                hw[(q * 4 + r) * HS + dt * 16 + l15] = f2bf(fv[dt][r]);
        LGK();                               // f visible

        // ---- GEMM3: 16px x 208p x 64d -> running min ----
        bf16x8 fa0 = *(const bf16x8*)&hw[l15 * HS + q * 8];
        bf16x8 fa1 = *(const bf16x8*)&hw[l15 * HS + 32 + q * 8];
        #pragma unroll
        for (int pt = 0; pt < 13; ++pt) {
            bf16x8 pb0 = *(const bf16x8*)&protolds[(pt * 16 + l15) * HS + q * 8];
            bf16x8 pb1 = *(const bf16x8*)&protolds[(pt * 16 + l15) * HS + 32 + q * 8];
            f32x4 a3 = {0.f, 0.f, 0.f, 0.f};
            a3 = MFMA(fa0, pb0, a3);
            a3 = MFMA(fa1, pb1, a3);
            float m = 1e30f;
            #pragma unroll
            for (int r = 0; r < 4; ++r)
                m = fminf(m, fmaxf(s2v[r] - 2.f * a3[r] + p2r[pt], 0.f));
            rmin[pt] = fminf(rmin[pt], m);
        }
    }

    // ---- final reduction: regs -> bmin ----
    #pragma unroll
    for (int pt = 0; pt < 13; ++pt) {
        float m = rmin[pt];
        m = fminf(m, __shfl_xor(m, 16, 64));
        m = fminf(m, __shfl_xor(m, 32, 64));
        if (lane < 16) atomicMin(&bmin[pt * 16 + l15], __float_as_uint(m));
    }
    __syncthreads();

    // ---------------- epilogue: min_distances + logits ----------------
    if (t < NP) {
        out[NIMG * NCLS + (size_t)n * NP + t] = __uint_as_float(bmin[t]);
    }
    if (t < 320) {
        int c = t >> 5, j = t & 31;
        float acc = 0.f;
        for (int p = j; p < NP; p += 32)
            acc += __uint_as_float(bmin[p]) * lastW[c * NP + p];
        acc += __shfl_xor(acc, 1, 32);
        acc += __shfl_xor(acc, 2, 32);
        acc += __shfl_xor(acc, 4, 32);
        acc += __shfl_xor(acc, 8, 32);
        acc += __shfl_xor(acc, 16, 32);
        if (j == 0) out[(size_t)n * NCLS + c] = -acc + lastb[c];
    }
}

extern "C" void kernel_launch(void* const* d_in, const int* in_sizes, int n_in,
                              void* d_out, int out_size, void* d_ws, size_t ws_size,
                              hipStream_t stream) {
    const float* x     = (const float*)d_in[0];
    const float* W1    = (const float*)d_in[1];
    const float* b1    = (const float*)d_in[2];
    const float* W2    = (const float*)d_in[3];
    const float* b2    = (const float*)d_in[4];
    const float* proto = (const float*)d_in[5];
    const float* lastW = (const float*)d_in[6];
    const float* lastb = (const float*)d_in[7];
    float* out = (float*)d_out;

    proto_fused_kernel<<<dim3(NIMG), dim3(512), 0, stream>>>(
        x, W1, b1, W2, b2, proto, lastW, lastb, out);
}